// Round 2
// 526.164 us; speedup vs baseline: 1.0065x; 1.0065x over previous
//
#include <hip/hip_runtime.h>
#include <hip/hip_bf16.h>
#include <stdint.h>

#define B_  4096
#define IN_ 1024
#define H_  2048
#define K_  (IN_ + H_)   // 3072
#define N_  (5 * H_)     // 10240

#define BM 128
#define BJ 32            // per-gate columns per block (5 gates -> 160 B-rows)
#define BK 32
#define NT 96            // K_/BK K-steps

typedef __attribute__((ext_vector_type(8))) short   short8;
typedef __attribute__((ext_vector_type(4))) float   f32x4;
typedef __attribute__((ext_vector_type(8))) unsigned short ushort8;

// ---------- helpers ----------
__device__ __forceinline__ unsigned short f2bf(float f) {
  union { float f; unsigned u; } cv; cv.f = f;
  unsigned u = cv.u;
  u += 0x7fffu + ((u >> 16) & 1u);   // round-to-nearest-even
  return (unsigned short)(u >> 16);
}

__device__ __forceinline__ void async16(const unsigned short* g, unsigned short* l) {
  __builtin_amdgcn_global_load_lds(
      (const __attribute__((address_space(1))) unsigned int*)g,
      (__attribute__((address_space(3))) unsigned int*)(void*)l,
      16, 0, 0);
}

__device__ __forceinline__ float fsig(float x) {
  return __builtin_amdgcn_rcpf(1.f + __expf(-x));   // rcp(inf)=0 -> safe
}
__device__ __forceinline__ float ftanh(float x) {
  return 1.f - 2.f * __builtin_amdgcn_rcpf(__expf(2.f * x) + 1.f);
}

// ---------- kernel 1: combined = bf16([x | h_prev])  [B_, K_] ----------
__global__ void build_combined(const float* __restrict__ x,
                               const float* __restrict__ h,
                               unsigned short* __restrict__ out) {
  const int row = blockIdx.x;
  const float4* xr = (const float4*)(x + (size_t)row * IN_);
  const float4* hr = (const float4*)(h + (size_t)row * H_);
  uint2* orow = (uint2*)(out + (size_t)row * K_);
  for (int c = threadIdx.x; c < K_ / 4; c += 256) {
    float4 v = (c < IN_ / 4) ? xr[c] : hr[c - IN_ / 4];
    uint2 p;
    p.x = (unsigned)f2bf(v.x) | ((unsigned)f2bf(v.y) << 16);
    p.y = (unsigned)f2bf(v.z) | ((unsigned)f2bf(v.w) << 16);
    orow[c] = p;
  }
}

// ---------- kernel 2: Wt[n][k] = bf16(W[k][n])  (64x64 LDS-tiled) ----------
__global__ __launch_bounds__(256) void transpose_convert(
    const float* __restrict__ W, unsigned short* __restrict__ Wt) {
  __shared__ float tile[64][65];
  const int n0 = blockIdx.x * 64;          // 160 blocks
  const int k0 = blockIdx.y * 64;          // 48 blocks
  const int t  = threadIdx.x;

  const int r0 = t >> 4;                   // 0..15
  const int c4 = t & 15;                   // float4 col index
  #pragma unroll
  for (int i = 0; i < 4; ++i) {
    const int kk = i * 16 + r0;
    const float4 v = *(const float4*)&W[(size_t)(k0 + kk) * N_ + n0 + c4 * 4];
    float* dst = &tile[kk][c4 * 4];
    dst[0] = v.x; dst[1] = v.y; dst[2] = v.z; dst[3] = v.w;
  }
  __syncthreads();

  #pragma unroll
  for (int i = 0; i < 2; ++i) {
    const int c2 = t + i * 256;
    const int nn = c2 >> 3;
    const int kc = (c2 & 7) * 8;
    ushort8 p;
    #pragma unroll
    for (int u = 0; u < 8; ++u) p[u] = f2bf(tile[kc + u][nn]);
    *(ushort8*)&Wt[(size_t)(n0 + nn) * K_ + k0 + kc] = p;
  }
}

// ---------- kernel 3: fused GEMM + xLSTM gate epilogue ----------
// Schedule (T3+T4+T5, resubmit after container-level infra failure):
//   - double-buffered LDS (2x18KB), staging issued 2 K-tiles ahead
//   - counted s_waitcnt vmcnt(5/4) instead of __syncthreads' vmcnt(0) drain
//     (never 0 in main loop; T4, m218) -> global-load latency hides under
//     ~2 K-steps of MFMA instead of being exposed every step
//   - raw s_barrier (no implicit drain); explicit lgkmcnt(0)+sched_barrier
//     before buffer-overwrite barrier (read-before-write hazard)
//   - s_setprio(1) around the MFMA cluster (T5)
// __launch_bounds__(256,3): unified VGPR+AGPR kept so 3 waves/SIMD resident.
__global__ __launch_bounds__(256, 3) void gemm_fused(
    const unsigned short* __restrict__ A,   // [B_, K_] bf16
    const unsigned short* __restrict__ Bt,  // [N_, K_] bf16
    const float* __restrict__ c_prev,       // [B_, H_]
    const float* __restrict__ bias,         // [5*H_]
    float* __restrict__ out)                // ht | ct
{
  __shared__ unsigned short As[2][BM * BK];        // 2 x 8 KB, pad-free (lds-DMA)
  __shared__ unsigned short Bs[2][5 * BJ * BK];    // 2 x 10 KB

  const int tid  = threadIdx.x;
  const int wave = tid >> 6;
  const int lane = tid & 63;
  const int quad = lane >> 4;
  const int lr   = lane & 15;

  const int tile_m = blockIdx.x >> 6;     // 32 m-tiles
  const int tile_j = blockIdx.x & 63;     // 64 j-tiles
  const int m0 = tile_m * BM;
  const int j0 = tile_j * BJ;

  const int wm = (wave & 1) * 64;         // row half within block
  const int wn = (wave >> 1) * 16;        // col half within j-tile

  f32x4 acc[4][5];
  #pragma unroll
  for (int mi = 0; mi < 4; ++mi)
    #pragma unroll
    for (int g = 0; g < 5; ++g)
      acc[mi][g] = (f32x4){0.f, 0.f, 0.f, 0.f};

  // staging: 16-row chunks of 64B rows; XOR chunk swizzle so LDS slot
  // (lane&3) of row r holds chunk (lane&3)^((r>>1)&3). Measured: 0 bank
  // conflicts — do not touch.
  const int lrow4 = lane >> 2;                                  // 0..15
  const int scol  = ((lane & 3) ^ ((lane >> 3) & 3)) * 8;       // shorts
  const size_t k16 = (size_t)16 * K_;

  // A: wave stages its own 32 rows (2 chunks)
  const unsigned short* aP =
      A + ((size_t)(m0 + wave * 32 + lrow4)) * K_ + scol;
  const int aL0o = (wave * 32) * BK;
  const int aL1o = (wave * 32 + 16) * BK;

  // B: chunk c (0..9) -> gate c>>1, half c&1; wave w owns {2w, 2w+1},
  // waves 0/1 additionally own {8, 9}.  Wave-uniform, fully precomputed.
  const unsigned short* bBase = Bt + ((size_t)(j0 + lrow4)) * K_ + scol;
  const unsigned short* bP0 = bBase + (size_t)wave * H_ * K_;      // c=2w
  const unsigned short* bP2 = bBase + ((size_t)4 * H_ + wave * 16) * K_; // c=8+w
  const int bL0o = (wave * 32) * BK;
  const int bL1o = (wave * 32 + 16) * BK;
  const int bL2o = ((8 + wave) * 16) * BK;
  const bool doTail = (wave < 2);          // 5 loads/tile for waves 0-1, else 4

  #define STAGE(tt, bb) do {                          \
    const int ko_ = (tt) * BK;                        \
    async16(aP + ko_,        &As[(bb)][aL0o]);        \
    async16(aP + k16 + ko_,  &As[(bb)][aL1o]);        \
    async16(bP0 + ko_,       &Bs[(bb)][bL0o]);        \
    async16(bP0 + k16 + ko_, &Bs[(bb)][bL1o]);        \
    if (doTail) async16(bP2 + ko_, &Bs[(bb)][bL2o]);  \
  } while (0)

  // prologue: tiles 0 and 1 in flight before the loop
  STAGE(0, 0);
  STAGE(1, 1);

  // fragment read slot: quad ^ ((lr>>1)&3) (row bases are multiples of 16)
  const int rslot = (quad ^ ((lr >> 1) & 3)) * 8;               // shorts

  #pragma unroll 2
  for (int t = 0; t < NT; ++t) {
    const int cur = t & 1;

    // counted wait: retire tile t's 5(4) loads; tile t+1's stay in flight.
    if (t == NT - 1)     asm volatile("s_waitcnt vmcnt(0)" ::: "memory");
    else if (doTail)     asm volatile("s_waitcnt vmcnt(5)" ::: "memory");
    else                 asm volatile("s_waitcnt vmcnt(4)" ::: "memory");
    __builtin_amdgcn_s_barrier();          // all waves' tile-t loads landed

    short8 af[4], bf[5];
    #pragma unroll
    for (int mi = 0; mi < 4; ++mi)
      af[mi] = *(const short8*)&As[cur][(wm + mi * 16 + lr) * BK + rslot];
    #pragma unroll
    for (int g = 0; g < 5; ++g)
      bf[g] = *(const short8*)&Bs[cur][(g * 32 + wn + lr) * BK + rslot];

    // drain my ds_reads, then barrier: after this, buf[cur] is overwritable.
    asm volatile("s_waitcnt lgkmcnt(0)" ::: "memory");
    __builtin_amdgcn_sched_barrier(0);
    __builtin_amdgcn_s_barrier();

    if (t < NT - 2) STAGE(t + 2, cur);     // issue next-next tile, no wait
    __builtin_amdgcn_sched_barrier(0);     // pin: issue stages before MFMAs

    __builtin_amdgcn_s_setprio(1);
    #pragma unroll
    for (int mi = 0; mi < 4; ++mi)
      #pragma unroll
      for (int g = 0; g < 5; ++g)
        acc[mi][g] = __builtin_amdgcn_mfma_f32_16x16x32_bf16(
            af[mi], bf[g], acc[mi][g], 0, 0, 0);
    __builtin_amdgcn_s_setprio(0);
  }
  #undef STAGE

  // ---- fused epilogue: all 5 gates in-lane, fp32 throughout ----
  const int col = j0 + wn + lr;                    // 0..H_-1
  float bb[5];
  #pragma unroll
  for (int g = 0; g < 5; ++g) bb[g] = bias[g * H_ + col];

  #pragma unroll
  for (int mi = 0; mi < 4; ++mi) {
    const int rbase = m0 + wm + mi * 16 + quad * 4;
    float cp[4];
    #pragma unroll
    for (int r = 0; r < 4; ++r)
      cp[r] = c_prev[(size_t)(rbase + r) * H_ + col];
    #pragma unroll
    for (int r = 0; r < 4; ++r) {
      const float ft = fsig(acc[mi][0][r] + bb[0]);
      const float it = fsig(acc[mi][1][r] + bb[1]);
      const float ch = ftanh(acc[mi][2][r] + bb[2]);
      const float ot = fsig(acc[mi][3][r] + bb[3]);
      const float et = fsig(acc[mi][4][r] + bb[4]);
      const float ct = ft * cp[r] + it * ch;
      const float th = ftanh(ct);
      float ht = ot * th;
      ht = et * __expf(ht) + (1.f - et) * ht;
      out[(size_t)(rbase + r) * H_ + col] = ht;
      out[(size_t)B_ * H_ + (size_t)(rbase + r) * H_ + col] = ct;
    }
  }
}

// ---------- launcher ----------
extern "C" void kernel_launch(void* const* d_in, const int* in_sizes, int n_in,
                              void* d_out, int out_size, void* d_ws, size_t ws_size,
                              hipStream_t stream) {
  const float* x = (const float*)d_in[0];
  const float* h = (const float*)d_in[1];
  const float* c = (const float*)d_in[2];
  const float* W = (const float*)d_in[3];
  const float* b = (const float*)d_in[4];
  float* out = (float*)d_out;

  char* ws = (char*)d_ws;
  unsigned short* combined = (unsigned short*)ws;                  // 24 MB
  unsigned short* Wt = (unsigned short*)(ws + (size_t)25165824);   // 60 MB

  build_combined<<<B_, 256, 0, stream>>>(x, h, combined);
  transpose_convert<<<dim3(N_ / 64, K_ / 64), 256, 0, stream>>>(W, Wt);
  gemm_fused<<<(B_ / BM) * (H_ / BJ), 256, 0, stream>>>(combined, Wt, c, b, out);
}